// Round 6
// baseline (971.087 us; speedup 1.0000x reference)
//
#include <hip/hip_runtime.h>

#define N_NODES 8192
#define N_EDGES 65536
#define LAT 128
#define GEN 944
#define ECOLS 816   // columns of env_ij_w actually used (0..816)
#define ENVN 48
#define LINN 768
#define MULT 16
#define SPH 9
#define XROW 144  // MULT*SPH

#define EM 16      // edges per block in k_edge / k_score
#define NWT 51     // W_rs tiles (816/16)
#define WTCOLS 816 // Wt columns (W_rs only now)
#define WPAD 824   // w_lds row stride (bf16 elems), padded vs 816

// ---- workspace layout (float offsets); total ~68 MB, well below proven size.
#define OFF_WT    ((size_t)0)                             // 816*128 ushort = 52224 fl
#define OFF_ENV   ((size_t)52224)                         // N*816  env_node
#define OFF_KN    (OFF_ENV  + (size_t)N_NODES*ECOLS)      // N*256  Knode
#define OFF_EX    (OFF_KN   + (size_t)N_NODES*256)        // E*16   scores->ex
#define OFF_DH    (OFF_EX   + (size_t)N_EDGES*MULT)       // N*128  delta_h   (zeroed)
#define OFF_DX    (OFF_DH   + (size_t)N_NODES*LAT)        // N*144  delta_X   (zeroed)
#define OFF_DEN   (OFF_DX   + (size_t)N_NODES*XROW)       // N*16   den       (zeroed)
#define OFF_NMAX  (OFF_DEN  + (size_t)N_NODES*MULT)       // N*16   max keys  (zeroed)
#define OFF_XBUF  (OFF_NMAX + (size_t)N_NODES*MULT)       // E*144  x (bf16 ushort)

typedef __attribute__((ext_vector_type(8))) short bf16x8;
typedef __attribute__((ext_vector_type(4))) float f32x4;

__device__ __forceinline__ unsigned fkey(float f) {
  unsigned u = __float_as_uint(f);
  return (u & 0x80000000u) ? ~u : (u | 0x80000000u);
}
__device__ __forceinline__ float fdecode(unsigned u) {
  u = (u & 0x80000000u) ? (u & 0x7fffffffu) : ~u;
  return __uint_as_float(u);
}
__device__ __forceinline__ ushort f2b(float f) {  // f32->bf16 RNE
  unsigned u = __float_as_uint(f);
  return (ushort)((u + 0x7FFFu + ((u >> 16) & 1u)) >> 16);
}
__device__ __forceinline__ float b2f(ushort u) {
  return __uint_as_float(((unsigned)u) << 16);
}

// ---------------- weight transpose+cvt: Wt[c][k] = bf16(W_rs[:,c]), c<816
__global__ __launch_bounds__(128) void k_wt(
    const float* __restrict__ W_rs, ushort* __restrict__ Wt) {
  int c = blockIdx.x;   // 0..815
  int k = threadIdx.x;  // 0..127
  Wt[(size_t)c * 128 + k] = f2b(W_rs[(size_t)k * GEN + c]);
}

// ---------------- per-node precompute: env_node = silu(h@W1)@W2 (816 cols), Knode = h@W_key
__global__ __launch_bounds__(256) void k_node(
    const float* __restrict__ h, const float* __restrict__ W1,
    const float* __restrict__ W2, const float* __restrict__ Wk,
    float* __restrict__ env_node, float* __restrict__ Knode) {
  __shared__ float h_lds[8][LAT];
  __shared__ float s_lds[8][LAT];
  const int tid = threadIdx.x;
  const int nb = blockIdx.x * 8;

  { int o = tid * 4, e = o >> 7, k = o & 127;
    *(float4*)&h_lds[e][k] = *(const float4*)&h[(size_t)(nb + e) * LAT + k]; }
  __syncthreads();

  { // u = h@W1, silu -> s_lds
    int e = tid >> 5, c4 = (tid & 31) * 4;
    float a0 = 0, a1 = 0, a2 = 0, a3 = 0;
    for (int k0 = 0; k0 < LAT; k0 += 4) {
      float4 tv = *(float4*)&h_lds[e][k0];
      float4 w0 = *(const float4*)&W1[(k0 + 0) * LAT + c4];
      float4 w1 = *(const float4*)&W1[(k0 + 1) * LAT + c4];
      float4 w2 = *(const float4*)&W1[(k0 + 2) * LAT + c4];
      float4 w3 = *(const float4*)&W1[(k0 + 3) * LAT + c4];
      a0 += tv.x * w0.x + tv.y * w1.x + tv.z * w2.x + tv.w * w3.x;
      a1 += tv.x * w0.y + tv.y * w1.y + tv.z * w2.y + tv.w * w3.y;
      a2 += tv.x * w0.z + tv.y * w1.z + tv.z * w2.z + tv.w * w3.z;
      a3 += tv.x * w0.w + tv.y * w1.w + tv.z * w2.w + tv.w * w3.w;
    }
    s_lds[e][c4 + 0] = a0 / (1.f + expf(-a0));
    s_lds[e][c4 + 1] = a1 / (1.f + expf(-a1));
    s_lds[e][c4 + 2] = a2 / (1.f + expf(-a2));
    s_lds[e][c4 + 3] = a3 / (1.f + expf(-a3));
  }
  { // Knode = h@W_key
    int e = tid >> 5;
#pragma unroll
    for (int t2 = 0; t2 < 2; ++t2) {
      int c4 = ((tid & 31) + 32 * t2) * 4;
      float a0 = 0, a1 = 0, a2 = 0, a3 = 0;
      for (int k0 = 0; k0 < LAT; k0 += 4) {
        float4 tv = *(float4*)&h_lds[e][k0];
        float4 w0 = *(const float4*)&Wk[(k0 + 0) * 256 + c4];
        float4 w1 = *(const float4*)&Wk[(k0 + 1) * 256 + c4];
        float4 w2 = *(const float4*)&Wk[(k0 + 2) * 256 + c4];
        float4 w3 = *(const float4*)&Wk[(k0 + 3) * 256 + c4];
        a0 += tv.x * w0.x + tv.y * w1.x + tv.z * w2.x + tv.w * w3.x;
        a1 += tv.x * w0.y + tv.y * w1.y + tv.z * w2.y + tv.w * w3.y;
        a2 += tv.x * w0.z + tv.y * w1.z + tv.z * w2.z + tv.w * w3.z;
        a3 += tv.x * w0.w + tv.y * w1.w + tv.z * w2.w + tv.w * w3.w;
      }
      float4 r = make_float4(a0, a1, a2, a3);
      *(float4*)&Knode[(size_t)(nb + e) * 256 + c4] = r;
    }
  }
  __syncthreads();

  if (tid < 204) {  // env_node = s@W2 (816 cols)
    int c4 = tid * 4;
    float4 acc[8];
#pragma unroll
    for (int e = 0; e < 8; ++e) acc[e] = make_float4(0, 0, 0, 0);
    for (int k0 = 0; k0 < LAT; k0 += 4) {
      float4 w0 = *(const float4*)&W2[(size_t)(k0 + 0) * GEN + c4];
      float4 w1 = *(const float4*)&W2[(size_t)(k0 + 1) * GEN + c4];
      float4 w2 = *(const float4*)&W2[(size_t)(k0 + 2) * GEN + c4];
      float4 w3 = *(const float4*)&W2[(size_t)(k0 + 3) * GEN + c4];
#pragma unroll
      for (int e = 0; e < 8; ++e) {
        float4 tv = *(float4*)&s_lds[e][k0];
        acc[e].x += tv.x * w0.x + tv.y * w1.x + tv.z * w2.x + tv.w * w3.x;
        acc[e].y += tv.x * w0.y + tv.y * w1.y + tv.z * w2.y + tv.w * w3.y;
        acc[e].z += tv.x * w0.z + tv.y * w1.z + tv.z * w2.z + tv.w * w3.z;
        acc[e].w += tv.x * w0.w + tv.y * w1.w + tv.z * w2.w + tv.w * w3.w;
      }
    }
#pragma unroll
    for (int e = 0; e < 8; ++e)
      *(float4*)&env_node[(size_t)(nb + e) * ECOLS + c4] = acc[e];
  }
}

// ---------------- MFMA edge kernel (split-precision A, W_rs tiles only)
// w = ((t_hi+t_lo)@W_rs)*env_j -> bf16 LDS (+delta_h atomics cols<128);
// then x = env_weighter + eq_linear.
__global__ __launch_bounds__(256) void k_edge(
    const float* __restrict__ t_ij, const float* __restrict__ X,
    const float* __restrict__ sph, const int* __restrict__ ectr,
    const int* __restrict__ enbr, const ushort* __restrict__ Wt,
    const float* __restrict__ env_node, float* __restrict__ delta_h,
    ushort* __restrict__ x_buf) {
  __shared__ ushort w_lds[EM][WPAD];        // env_ij_w cols 0..816, bf16
  __shared__ float xj_lds[EM][SPH][16];     // X[j] transposed: [s][v]
  __shared__ float sph_lds[EM][12];
  __shared__ int i_lds[EM], j_lds[EM];
  const int tid = threadIdx.x;
  const int lane = tid & 63;
  const int wid = tid >> 6;
  const int eb = blockIdx.x * EM;
  const int r15 = lane & 15, kg = lane >> 4;

  if (tid < EM) { i_lds[tid] = ectr[eb + tid]; j_lds[tid] = enbr[eb + tid]; }
  if (tid < EM * SPH) {
    int e = tid / 9, s = tid % 9;
    sph_lds[e][s] = sph[(size_t)(eb + e) * SPH + s];
  }
  for (int o = tid; o < EM * XROW; o += 256) {  // transpose-stage X[j]
    int e = o / XROW, rr = o % XROW, v = rr / 9, s = rr % 9;
    xj_lds[e][s][v] = X[(size_t)enbr[eb + e] * XROW + rr];
  }

  // A fragments (hi + residual lo); all 4 waves hold the same 16 t rows
  bf16x8 ahi[4], alo[4];
#pragma unroll
  for (int c = 0; c < 4; ++c) {
    const float* src = &t_ij[(size_t)(eb + r15) * LAT + c * 32 + kg * 8];
    float f[8];
    *(float4*)&f[0] = *(const float4*)src;
    *(float4*)&f[4] = *(const float4*)(src + 4);
    bf16x8 hh, ll;
#pragma unroll
    for (int d = 0; d < 8; ++d) {
      ushort hb = f2b(f[d]);
      hh[d] = hb;
      ll[d] = f2b(f[d] - b2f(hb));
    }
    ahi[c] = hh; alo[c] = ll;
  }
  __syncthreads();

  for (int tn = wid; tn < NWT; tn += 4) {
    const ushort* b0 = &Wt[(size_t)(tn * 16 + r15) * 128 + kg * 8];
    f32x4 acc = {0.f, 0.f, 0.f, 0.f};
#pragma unroll
    for (int c = 0; c < 4; ++c) {
      bf16x8 b = *(const bf16x8*)(b0 + c * 32);
      acc = __builtin_amdgcn_mfma_f32_16x16x32_bf16(ahi[c], b, acc, 0, 0, 0);
      acc = __builtin_amdgcn_mfma_f32_16x16x32_bf16(alo[c], b, acc, 0, 0, 0);
    }
    int col = tn * 16 + r15;
#pragma unroll
    for (int g = 0; g < 4; ++g) {
      int row = kg * 4 + g;
      int j = j_lds[row];
      float v = acc[g] * env_node[(size_t)j * ECOLS + col];
      w_lds[row][col] = f2b(v);
      if (tn < 8)
        atomicAdd(&delta_h[(size_t)i_lds[row] * LAT + col], v);
    }
  }
  __syncthreads();

  // x = delta_spharm + delta_eq: thread = (edge e, mult m); store bf16
  {
    int e = tid >> 4, m = tid & 15;
    float lw[3][16], ew[3];
#pragma unroll
    for (int ir = 0; ir < 3; ++ir) {
      const ushort* p = &w_lds[e][ENVN + ir * 256 + m * 16];
      uint4 q0 = *(const uint4*)p;
      uint4 q1 = *(const uint4*)(p + 8);
      unsigned qq[8] = {q0.x, q0.y, q0.z, q0.w, q1.x, q1.y, q1.z, q1.w};
#pragma unroll
      for (int d = 0; d < 8; ++d) {
        lw[ir][2 * d]     = __uint_as_float(qq[d] << 16);
        lw[ir][2 * d + 1] = __uint_as_float(qq[d] & 0xFFFF0000u);
      }
      ew[ir] = b2f(w_lds[e][ir * 16 + m]);
    }
    ushort* xp = &x_buf[((size_t)(eb + e) * MULT + m) * SPH];
#pragma unroll
    for (int s = 0; s < SPH; ++s) {
      int ir = (s == 0) ? 0 : ((s < 4) ? 1 : 2);
      const float* xr = xj_lds[e][s];
      float acc = sph_lds[e][s] * ew[ir];
#pragma unroll
      for (int v4 = 0; v4 < 4; ++v4) {
        float4 xv = *(const float4*)&xr[v4 * 4];
        acc += 0.25f * (lw[ir][v4 * 4 + 0] * xv.x + lw[ir][v4 * 4 + 1] * xv.y +
                        lw[ir][v4 * 4 + 2] * xv.z + lw[ir][v4 * 4 + 3] * xv.w);
      }
      xp[s] = f2b(acc);
    }
  }
}

// ---------------- f32 VALU scores (round-2-validated math):
// thread (e,m): Q[m,:] = t[e]@Wq[:,m*16..], score = 4*Q·K[j][m,:]
__global__ __launch_bounds__(256) void k_score(
    const float* __restrict__ t_ij, const int* __restrict__ ectr,
    const int* __restrict__ enbr, const float* __restrict__ Wq,
    const float* __restrict__ Knode, float* __restrict__ ex_buf,
    unsigned* __restrict__ nmax) {
  __shared__ float t_lds[EM][LAT];
  const int tid = threadIdx.x;
  const int eb = blockIdx.x * EM;
  { int o = tid * 8, e = o >> 7, k = o & 127;
    *(float4*)&t_lds[e][k]     = *(const float4*)&t_ij[(size_t)(eb + e) * LAT + k];
    *(float4*)&t_lds[e][k + 4] = *(const float4*)&t_ij[(size_t)(eb + e) * LAT + k + 4]; }
  __syncthreads();

  const int e = tid >> 4, m = tid & 15;
  const int j = enbr[eb + e];
  float q[16];
#pragma unroll
  for (int hh = 0; hh < 16; ++hh) q[hh] = 0.f;
#pragma unroll 4
  for (int k = 0; k < LAT; ++k) {
    float tv = t_lds[e][k];
    const float* wr = &Wq[(size_t)k * 256 + m * 16];
    float4 w0 = *(const float4*)wr;
    float4 w1 = *(const float4*)(wr + 4);
    float4 w2 = *(const float4*)(wr + 8);
    float4 w3 = *(const float4*)(wr + 12);
    q[0] += tv * w0.x;  q[1] += tv * w0.y;  q[2] += tv * w0.z;  q[3] += tv * w0.w;
    q[4] += tv * w1.x;  q[5] += tv * w1.y;  q[6] += tv * w1.z;  q[7] += tv * w1.w;
    q[8] += tv * w2.x;  q[9] += tv * w2.y;  q[10] += tv * w2.z; q[11] += tv * w2.w;
    q[12] += tv * w3.x; q[13] += tv * w3.y; q[14] += tv * w3.z; q[15] += tv * w3.w;
  }
  const float* kn = &Knode[(size_t)j * 256 + m * 16];
  float acc = 0.f;
#pragma unroll
  for (int hh = 0; hh < 16; ++hh) acc += q[hh] * kn[hh];
  float sc = 4.f * acc;
  ex_buf[(size_t)(eb + e) * MULT + m] = sc;
  atomicMax(&nmax[ectr[eb + e] * MULT + m], fkey(sc));
}

// ---------------- softmax pass 2: ex = exp(s - max), den scatter
__global__ __launch_bounds__(256) void k_den(
    const int* __restrict__ ectr, const unsigned* __restrict__ nmax,
    float* __restrict__ ex_buf, float* __restrict__ den) {
  int idx = blockIdx.x * 256 + threadIdx.x;
  int e = idx >> 4, m = idx & 15;
  int i = ectr[e];
  float mval = fdecode(nmax[i * MULT + m]);
  float ex = expf(ex_buf[idx] - mval);
  ex_buf[idx] = ex;
  atomicAdd(&den[i * MULT + m], ex);
}

// ---------------- delta_X scatter: delta_X[i] += x * alpha
__global__ __launch_bounds__(256) void k_dx(
    const int* __restrict__ ectr, const float* __restrict__ ex_buf,
    const float* __restrict__ den, const ushort* __restrict__ x_buf,
    float* __restrict__ delta_X) {
  size_t idx = (size_t)blockIdx.x * 256 + threadIdx.x;
  int e = (int)(idx / XROW), r = (int)(idx % XROW), m = r / SPH;
  int i = ectr[e];
  float alpha = ex_buf[(size_t)e * MULT + m] / (den[i * MULT + m] + 1e-20f);
  atomicAdd(&delta_X[(size_t)i * XROW + r], b2f(x_buf[idx]) * alpha);
}

// ---------------- h_new = LayerNorm(h + delta_h)
__global__ __launch_bounds__(64) void k_hout(
    const float* __restrict__ h, const float* __restrict__ dh,
    const float* __restrict__ gamma, const float* __restrict__ beta,
    float* __restrict__ out) {
  int n = blockIdx.x, lane = threadIdx.x;
  size_t base = (size_t)n * LAT + lane * 2;
  float2 hv = *(const float2*)&h[base];
  float2 dv = *(const float2*)&dh[base];
  float v0 = hv.x + dv.x, v1 = hv.y + dv.y;
  float s = v0 + v1, ss = v0 * v0 + v1 * v1;
#pragma unroll
  for (int o = 32; o; o >>= 1) { s += __shfl_xor(s, o); ss += __shfl_xor(ss, o); }
  float mean = s * (1.f / 128.f);
  float var = ss * (1.f / 128.f) - mean * mean;
  float inv = rsqrtf(var + 1e-5f);
  int c = lane * 2;
  out[base + 0] = (v0 - mean) * inv * gamma[c + 0] + beta[c + 0];
  out[base + 1] = (v1 - mean) * inv * gamma[c + 1] + beta[c + 1];
}

// ---------------- X_new = SO3-LayerNorm(X + delta_X)
__global__ __launch_bounds__(192) void k_xout(
    const float* __restrict__ X, const float* __restrict__ dX,
    float* __restrict__ out) {
  __shared__ float ssq[3];
  int n = blockIdx.x, tid = threadIdx.x;
  if (tid < 3) ssq[tid] = 0.f;
  __syncthreads();
  float val = 0.f; int ir = 0;
  if (tid < XROW) {
    val = X[(size_t)n * XROW + tid] + dX[(size_t)n * XROW + tid];
    int s = tid % SPH;
    ir = (s == 0) ? 0 : ((s < 4) ? 1 : 2);
    atomicAdd(&ssq[ir], val * val);
  }
  __syncthreads();
  if (tid < XROW) {
    const float cnt[3] = {16.f, 48.f, 80.f};
    float rms = sqrtf(ssq[ir] / cnt[ir] + 1e-5f);
    out[(size_t)n * XROW + tid] = val / rms;
  }
}

extern "C" void kernel_launch(void* const* d_in, const int* in_sizes, int n_in,
                              void* d_out, int out_size, void* d_ws, size_t ws_size,
                              hipStream_t stream) {
  const float* h    = (const float*)d_in[0];
  const float* X    = (const float*)d_in[1];
  const float* t_ij = (const float*)d_in[2];
  const float* sph  = (const float*)d_in[3];
  const int*   ectr = (const int*)d_in[5];
  const int*   enbr = (const int*)d_in[6];
  const float* W_rs = (const float*)d_in[7];
  const float* W1   = (const float*)d_in[8];
  const float* W2   = (const float*)d_in[9];
  const float* gam  = (const float*)d_in[10];
  const float* bet  = (const float*)d_in[11];
  const float* Wq   = (const float*)d_in[12];
  const float* Wk   = (const float*)d_in[13];
  float* out = (float*)d_out;
  float* ws  = (float*)d_ws;

  ushort*   Wt       = (ushort*)(ws + OFF_WT);
  float*    env_node = ws + OFF_ENV;
  float*    Knode    = ws + OFF_KN;
  float*    ex_buf   = ws + OFF_EX;
  float*    delta_h  = ws + OFF_DH;
  float*    delta_X  = ws + OFF_DX;
  float*    den      = ws + OFF_DEN;
  unsigned* nmax     = (unsigned*)(ws + OFF_NMAX);
  ushort*   x_buf    = (ushort*)(ws + OFF_XBUF);

  // zero delta_h, delta_X, den, nmax (contiguous; key 0 == -inf sentinel)
  hipMemsetAsync(delta_h, 0,
                 (size_t)N_NODES * (LAT + XROW + MULT + MULT) * sizeof(float), stream);
  // t_ij passthrough output
  hipMemcpyAsync(out + (size_t)N_NODES * (LAT + XROW), d_in[2],
                 (size_t)N_EDGES * LAT * sizeof(float),
                 hipMemcpyDeviceToDevice, stream);

  k_wt<<<WTCOLS, 128, 0, stream>>>(W_rs, Wt);
  k_node<<<N_NODES / 8, 256, 0, stream>>>(h, W1, W2, Wk, env_node, Knode);
  k_edge<<<N_EDGES / EM, 256, 0, stream>>>(t_ij, X, sph, ectr, enbr, Wt,
                                           env_node, delta_h, x_buf);
  k_score<<<N_EDGES / EM, 256, 0, stream>>>(t_ij, ectr, enbr, Wq, Knode,
                                            ex_buf, nmax);
  k_den<<<(N_EDGES * MULT) / 256, 256, 0, stream>>>(ectr, nmax, ex_buf, den);
  k_dx<<<((size_t)N_EDGES * XROW) / 256, 256, 0, stream>>>(ectr, ex_buf, den, x_buf, delta_X);
  k_hout<<<N_NODES, 64, 0, stream>>>(h, delta_h, gam, bet, out);
  k_xout<<<N_NODES, 192, 0, stream>>>(X, delta_X, out + (size_t)N_NODES * LAT);
}

// Round 7
// 594.582 us; speedup vs baseline: 1.6332x; 1.6332x over previous
//
#include <hip/hip_runtime.h>

#define N_NODES 8192
#define N_EDGES 65536
#define LAT 128
#define GEN 944
#define ECOLS 816   // columns of env_ij_w actually used (0..816)
#define ENVN 48
#define LINN 768
#define MULT 16
#define SPH 9
#define XROW 144  // MULT*SPH

#define EM 16      // edges per block in k_edge
#define NWT 51     // W_rs tiles (816/16)
#define WTCOLS 816 // Wt columns (W_rs only)
#define WPAD 824   // w_lds row stride (bf16 elems), padded vs 816

#define SB 64      // edges per k_score block
#define KC 16      // k-chunk rows staged per iteration

// ---- workspace layout (float offsets); total ~68 MB, well below proven size.
#define OFF_WT    ((size_t)0)                             // 816*128 ushort = 52224 fl
#define OFF_ENV   ((size_t)52224)                         // N*816  env_node
#define OFF_KN    (OFF_ENV  + (size_t)N_NODES*ECOLS)      // N*256  Knode
#define OFF_EX    (OFF_KN   + (size_t)N_NODES*256)        // E*16   scores->ex
#define OFF_DH    (OFF_EX   + (size_t)N_EDGES*MULT)       // N*128  delta_h   (zeroed)
#define OFF_DX    (OFF_DH   + (size_t)N_NODES*LAT)        // N*144  delta_X   (zeroed)
#define OFF_DEN   (OFF_DX   + (size_t)N_NODES*XROW)       // N*16   den       (zeroed)
#define OFF_NMAX  (OFF_DEN  + (size_t)N_NODES*MULT)       // N*16   max keys  (zeroed)
#define OFF_XBUF  (OFF_NMAX + (size_t)N_NODES*MULT)       // E*144  x (bf16 ushort)

typedef __attribute__((ext_vector_type(8))) short bf16x8;
typedef __attribute__((ext_vector_type(4))) float f32x4;

__device__ __forceinline__ unsigned fkey(float f) {
  unsigned u = __float_as_uint(f);
  return (u & 0x80000000u) ? ~u : (u | 0x80000000u);
}
__device__ __forceinline__ float fdecode(unsigned u) {
  u = (u & 0x80000000u) ? (u & 0x7fffffffu) : ~u;
  return __uint_as_float(u);
}
__device__ __forceinline__ ushort f2b(float f) {  // f32->bf16 RNE
  unsigned u = __float_as_uint(f);
  return (ushort)((u + 0x7FFFu + ((u >> 16) & 1u)) >> 16);
}
__device__ __forceinline__ float b2f(ushort u) {
  return __uint_as_float(((unsigned)u) << 16);
}

// ---------------- weight transpose+cvt: Wt[c][k] = bf16(W_rs[:,c]), c<816
__global__ __launch_bounds__(128) void k_wt(
    const float* __restrict__ W_rs, ushort* __restrict__ Wt) {
  int c = blockIdx.x;   // 0..815
  int k = threadIdx.x;  // 0..127
  Wt[(size_t)c * 128 + k] = f2b(W_rs[(size_t)k * GEN + c]);
}

// ---------------- per-node precompute: env_node = silu(h@W1)@W2 (816 cols), Knode = h@W_key
__global__ __launch_bounds__(256) void k_node(
    const float* __restrict__ h, const float* __restrict__ W1,
    const float* __restrict__ W2, const float* __restrict__ Wk,
    float* __restrict__ env_node, float* __restrict__ Knode) {
  __shared__ float h_lds[8][LAT];
  __shared__ float s_lds[8][LAT];
  const int tid = threadIdx.x;
  const int nb = blockIdx.x * 8;

  { int o = tid * 4, e = o >> 7, k = o & 127;
    *(float4*)&h_lds[e][k] = *(const float4*)&h[(size_t)(nb + e) * LAT + k]; }
  __syncthreads();

  { // u = h@W1, silu -> s_lds
    int e = tid >> 5, c4 = (tid & 31) * 4;
    float a0 = 0, a1 = 0, a2 = 0, a3 = 0;
    for (int k0 = 0; k0 < LAT; k0 += 4) {
      float4 tv = *(float4*)&h_lds[e][k0];
      float4 w0 = *(const float4*)&W1[(k0 + 0) * LAT + c4];
      float4 w1 = *(const float4*)&W1[(k0 + 1) * LAT + c4];
      float4 w2 = *(const float4*)&W1[(k0 + 2) * LAT + c4];
      float4 w3 = *(const float4*)&W1[(k0 + 3) * LAT + c4];
      a0 += tv.x * w0.x + tv.y * w1.x + tv.z * w2.x + tv.w * w3.x;
      a1 += tv.x * w0.y + tv.y * w1.y + tv.z * w2.y + tv.w * w3.y;
      a2 += tv.x * w0.z + tv.y * w1.z + tv.z * w2.z + tv.w * w3.z;
      a3 += tv.x * w0.w + tv.y * w1.w + tv.z * w2.w + tv.w * w3.w;
    }
    s_lds[e][c4 + 0] = a0 / (1.f + expf(-a0));
    s_lds[e][c4 + 1] = a1 / (1.f + expf(-a1));
    s_lds[e][c4 + 2] = a2 / (1.f + expf(-a2));
    s_lds[e][c4 + 3] = a3 / (1.f + expf(-a3));
  }
  { // Knode = h@W_key
    int e = tid >> 5;
#pragma unroll
    for (int t2 = 0; t2 < 2; ++t2) {
      int c4 = ((tid & 31) + 32 * t2) * 4;
      float a0 = 0, a1 = 0, a2 = 0, a3 = 0;
      for (int k0 = 0; k0 < LAT; k0 += 4) {
        float4 tv = *(float4*)&h_lds[e][k0];
        float4 w0 = *(const float4*)&Wk[(k0 + 0) * 256 + c4];
        float4 w1 = *(const float4*)&Wk[(k0 + 1) * 256 + c4];
        float4 w2 = *(const float4*)&Wk[(k0 + 2) * 256 + c4];
        float4 w3 = *(const float4*)&Wk[(k0 + 3) * 256 + c4];
        a0 += tv.x * w0.x + tv.y * w1.x + tv.z * w2.x + tv.w * w3.x;
        a1 += tv.x * w0.y + tv.y * w1.y + tv.z * w2.y + tv.w * w3.y;
        a2 += tv.x * w0.z + tv.y * w1.z + tv.z * w2.z + tv.w * w3.z;
        a3 += tv.x * w0.w + tv.y * w1.w + tv.z * w2.w + tv.w * w3.w;
      }
      float4 r = make_float4(a0, a1, a2, a3);
      *(float4*)&Knode[(size_t)(nb + e) * 256 + c4] = r;
    }
  }
  __syncthreads();

  if (tid < 204) {  // env_node = s@W2 (816 cols)
    int c4 = tid * 4;
    float4 acc[8];
#pragma unroll
    for (int e = 0; e < 8; ++e) acc[e] = make_float4(0, 0, 0, 0);
    for (int k0 = 0; k0 < LAT; k0 += 4) {
      float4 w0 = *(const float4*)&W2[(size_t)(k0 + 0) * GEN + c4];
      float4 w1 = *(const float4*)&W2[(size_t)(k0 + 1) * GEN + c4];
      float4 w2 = *(const float4*)&W2[(size_t)(k0 + 2) * GEN + c4];
      float4 w3 = *(const float4*)&W2[(size_t)(k0 + 3) * GEN + c4];
#pragma unroll
      for (int e = 0; e < 8; ++e) {
        float4 tv = *(float4*)&s_lds[e][k0];
        acc[e].x += tv.x * w0.x + tv.y * w1.x + tv.z * w2.x + tv.w * w3.x;
        acc[e].y += tv.x * w0.y + tv.y * w1.y + tv.z * w2.y + tv.w * w3.y;
        acc[e].z += tv.x * w0.z + tv.y * w1.z + tv.z * w2.z + tv.w * w3.z;
        acc[e].w += tv.x * w0.w + tv.y * w1.w + tv.z * w2.w + tv.w * w3.w;
      }
    }
#pragma unroll
    for (int e = 0; e < 8; ++e)
      *(float4*)&env_node[(size_t)(nb + e) * ECOLS + c4] = acc[e];
  }
}

// ---------------- MFMA edge kernel (split-precision A, W_rs tiles only)
// w = ((t_hi+t_lo)@W_rs)*env_j -> bf16 LDS (+delta_h atomics cols<128);
// then x = env_weighter + eq_linear.
__global__ __launch_bounds__(256) void k_edge(
    const float* __restrict__ t_ij, const float* __restrict__ X,
    const float* __restrict__ sph, const int* __restrict__ ectr,
    const int* __restrict__ enbr, const ushort* __restrict__ Wt,
    const float* __restrict__ env_node, float* __restrict__ delta_h,
    ushort* __restrict__ x_buf) {
  __shared__ ushort w_lds[EM][WPAD];        // env_ij_w cols 0..816, bf16
  __shared__ float xj_lds[EM][SPH][16];     // X[j] transposed: [s][v]
  __shared__ float sph_lds[EM][12];
  __shared__ int i_lds[EM], j_lds[EM];
  const int tid = threadIdx.x;
  const int lane = tid & 63;
  const int wid = tid >> 6;
  const int eb = blockIdx.x * EM;
  const int r15 = lane & 15, kg = lane >> 4;

  if (tid < EM) { i_lds[tid] = ectr[eb + tid]; j_lds[tid] = enbr[eb + tid]; }
  if (tid < EM * SPH) {
    int e = tid / 9, s = tid % 9;
    sph_lds[e][s] = sph[(size_t)(eb + e) * SPH + s];
  }
  for (int o = tid; o < EM * XROW; o += 256) {  // transpose-stage X[j]
    int e = o / XROW, rr = o % XROW, v = rr / 9, s = rr % 9;
    xj_lds[e][s][v] = X[(size_t)enbr[eb + e] * XROW + rr];
  }

  // A fragments (hi + residual lo); all 4 waves hold the same 16 t rows
  bf16x8 ahi[4], alo[4];
#pragma unroll
  for (int c = 0; c < 4; ++c) {
    const float* src = &t_ij[(size_t)(eb + r15) * LAT + c * 32 + kg * 8];
    float f[8];
    *(float4*)&f[0] = *(const float4*)src;
    *(float4*)&f[4] = *(const float4*)(src + 4);
    bf16x8 hh, ll;
#pragma unroll
    for (int d = 0; d < 8; ++d) {
      ushort hb = f2b(f[d]);
      hh[d] = hb;
      ll[d] = f2b(f[d] - b2f(hb));
    }
    ahi[c] = hh; alo[c] = ll;
  }
  __syncthreads();

  for (int tn = wid; tn < NWT; tn += 4) {
    const ushort* b0 = &Wt[(size_t)(tn * 16 + r15) * 128 + kg * 8];
    f32x4 acc = {0.f, 0.f, 0.f, 0.f};
#pragma unroll
    for (int c = 0; c < 4; ++c) {
      bf16x8 b = *(const bf16x8*)(b0 + c * 32);
      acc = __builtin_amdgcn_mfma_f32_16x16x32_bf16(ahi[c], b, acc, 0, 0, 0);
      acc = __builtin_amdgcn_mfma_f32_16x16x32_bf16(alo[c], b, acc, 0, 0, 0);
    }
    int col = tn * 16 + r15;
#pragma unroll
    for (int g = 0; g < 4; ++g) {
      int row = kg * 4 + g;
      int j = j_lds[row];
      float v = acc[g] * env_node[(size_t)j * ECOLS + col];
      w_lds[row][col] = f2b(v);
      if (tn < 8)
        atomicAdd(&delta_h[(size_t)i_lds[row] * LAT + col], v);
    }
  }
  __syncthreads();

  // x = delta_spharm + delta_eq: thread = (edge e, mult m); store bf16
  {
    int e = tid >> 4, m = tid & 15;
    float lw[3][16], ew[3];
#pragma unroll
    for (int ir = 0; ir < 3; ++ir) {
      const ushort* p = &w_lds[e][ENVN + ir * 256 + m * 16];
      uint4 q0 = *(const uint4*)p;
      uint4 q1 = *(const uint4*)(p + 8);
      unsigned qq[8] = {q0.x, q0.y, q0.z, q0.w, q1.x, q1.y, q1.z, q1.w};
#pragma unroll
      for (int d = 0; d < 8; ++d) {
        lw[ir][2 * d]     = __uint_as_float(qq[d] << 16);
        lw[ir][2 * d + 1] = __uint_as_float(qq[d] & 0xFFFF0000u);
      }
      ew[ir] = b2f(w_lds[e][ir * 16 + m]);
    }
    ushort* xp = &x_buf[((size_t)(eb + e) * MULT + m) * SPH];
#pragma unroll
    for (int s = 0; s < SPH; ++s) {
      int ir = (s == 0) ? 0 : ((s < 4) ? 1 : 2);
      const float* xr = xj_lds[e][s];
      float acc = sph_lds[e][s] * ew[ir];
#pragma unroll
      for (int v4 = 0; v4 < 4; ++v4) {
        float4 xv = *(const float4*)&xr[v4 * 4];
        acc += 0.25f * (lw[ir][v4 * 4 + 0] * xv.x + lw[ir][v4 * 4 + 1] * xv.y +
                        lw[ir][v4 * 4 + 2] * xv.z + lw[ir][v4 * 4 + 3] * xv.w);
      }
      xp[s] = f2b(acc);
    }
  }
}

// ---------------- f32 scores, LDS-tiled GEMM structure.
// Block: 64 edges, 256 threads. thread (eg=tid>>4, m=tid&15) computes
// Q[4 edges][16 h] f32; score = 4*Q·K[j]. Wq staged per 16-k chunk with
// block-rotation swizzle (phys_h4 = (h4 + m/2) & 3) -> 2-way (free) banks.
__global__ __launch_bounds__(256) void k_score(
    const float* __restrict__ t_ij, const int* __restrict__ ectr,
    const int* __restrict__ enbr, const float* __restrict__ Wq,
    const float* __restrict__ Knode, float* __restrict__ ex_buf,
    unsigned* __restrict__ nmax) {
  __shared__ float t_lds[SB][129];
  __shared__ float wq_lds[KC][260];
  const int tid = threadIdx.x;
  const int eb = blockIdx.x * SB;
  const int m = tid & 15, eg = tid >> 4;
  const int rot = (m >> 1) & 3;

  // stage t: 64 edges x 128 k (coalesced float4 reads)
#pragma unroll
  for (int p = 0; p < 8; ++p) {
    int qi = tid + p * 256;
    int e = qi >> 5, kq = (qi & 31) * 4;
    float4 v = *(const float4*)&t_ij[(size_t)(eb + e) * LAT + kq];
    t_lds[e][kq + 0] = v.x; t_lds[e][kq + 1] = v.y;
    t_lds[e][kq + 2] = v.z; t_lds[e][kq + 3] = v.w;
  }

  float qa[4][16];
#pragma unroll
  for (int e = 0; e < 4; ++e)
#pragma unroll
    for (int hh = 0; hh < 16; ++hh) qa[e][hh] = 0.f;

  for (int kc = 0; kc < LAT; kc += KC) {
    __syncthreads();
    // stage Wq[kc..kc+16) with rotation swizzle
#pragma unroll
    for (int p = 0; p < 4; ++p) {
      int idx = tid + p * 256;
      int kr = idx >> 6, c4 = (idx & 63) * 4;
      int mm = c4 >> 4, h4 = (c4 >> 2) & 3;
      int c4s = mm * 16 + ((h4 + (mm >> 1)) & 3) * 4;
      float4 v = *(const float4*)&Wq[(size_t)(kc + kr) * 256 + c4];
      *(float4*)&wq_lds[kr][c4s] = v;
    }
    __syncthreads();
#pragma unroll 2
    for (int kk = 0; kk < KC; ++kk) {
      float w[16];
#pragma unroll
      for (int i = 0; i < 4; ++i) {
        float4 wv = *(const float4*)&wq_lds[kk][m * 16 + ((i + rot) & 3) * 4];
        w[i * 4 + 0] = wv.x; w[i * 4 + 1] = wv.y;
        w[i * 4 + 2] = wv.z; w[i * 4 + 3] = wv.w;
      }
#pragma unroll
      for (int e = 0; e < 4; ++e) {
        float tv = t_lds[eg * 4 + e][kc + kk];
#pragma unroll
        for (int hh = 0; hh < 16; ++hh) qa[e][hh] += tv * w[hh];
      }
    }
  }

#pragma unroll
  for (int e = 0; e < 4; ++e) {
    int ee = eb + eg * 4 + e;
    int j = enbr[ee];
    const float* kn = &Knode[(size_t)j * 256 + m * 16];
    float4 k0 = *(const float4*)kn;
    float4 k1 = *(const float4*)(kn + 4);
    float4 k2 = *(const float4*)(kn + 8);
    float4 k3 = *(const float4*)(kn + 12);
    float acc =
        qa[e][0] * k0.x + qa[e][1] * k0.y + qa[e][2] * k0.z + qa[e][3] * k0.w +
        qa[e][4] * k1.x + qa[e][5] * k1.y + qa[e][6] * k1.z + qa[e][7] * k1.w +
        qa[e][8] * k2.x + qa[e][9] * k2.y + qa[e][10] * k2.z + qa[e][11] * k2.w +
        qa[e][12] * k3.x + qa[e][13] * k3.y + qa[e][14] * k3.z + qa[e][15] * k3.w;
    float sc = 4.f * acc;
    ex_buf[(size_t)ee * MULT + m] = sc;
    atomicMax(&nmax[ectr[ee] * MULT + m], fkey(sc));
  }
}

// ---------------- softmax pass 2: ex = exp(s - max), den scatter
__global__ __launch_bounds__(256) void k_den(
    const int* __restrict__ ectr, const unsigned* __restrict__ nmax,
    float* __restrict__ ex_buf, float* __restrict__ den) {
  int idx = blockIdx.x * 256 + threadIdx.x;
  int e = idx >> 4, m = idx & 15;
  int i = ectr[e];
  float mval = fdecode(nmax[i * MULT + m]);
  float ex = expf(ex_buf[idx] - mval);
  ex_buf[idx] = ex;
  atomicAdd(&den[i * MULT + m], ex);
}

// ---------------- delta_X scatter: delta_X[i] += x * alpha
__global__ __launch_bounds__(256) void k_dx(
    const int* __restrict__ ectr, const float* __restrict__ ex_buf,
    const float* __restrict__ den, const ushort* __restrict__ x_buf,
    float* __restrict__ delta_X) {
  size_t idx = (size_t)blockIdx.x * 256 + threadIdx.x;
  int e = (int)(idx / XROW), r = (int)(idx % XROW), m = r / SPH;
  int i = ectr[e];
  float alpha = ex_buf[(size_t)e * MULT + m] / (den[i * MULT + m] + 1e-20f);
  atomicAdd(&delta_X[(size_t)i * XROW + r], b2f(x_buf[idx]) * alpha);
}

// ---------------- h_new = LayerNorm(h + delta_h)
__global__ __launch_bounds__(64) void k_hout(
    const float* __restrict__ h, const float* __restrict__ dh,
    const float* __restrict__ gamma, const float* __restrict__ beta,
    float* __restrict__ out) {
  int n = blockIdx.x, lane = threadIdx.x;
  size_t base = (size_t)n * LAT + lane * 2;
  float2 hv = *(const float2*)&h[base];
  float2 dv = *(const float2*)&dh[base];
  float v0 = hv.x + dv.x, v1 = hv.y + dv.y;
  float s = v0 + v1, ss = v0 * v0 + v1 * v1;
#pragma unroll
  for (int o = 32; o; o >>= 1) { s += __shfl_xor(s, o); ss += __shfl_xor(ss, o); }
  float mean = s * (1.f / 128.f);
  float var = ss * (1.f / 128.f) - mean * mean;
  float inv = rsqrtf(var + 1e-5f);
  int c = lane * 2;
  out[base + 0] = (v0 - mean) * inv * gamma[c + 0] + beta[c + 0];
  out[base + 1] = (v1 - mean) * inv * gamma[c + 1] + beta[c + 1];
}

// ---------------- X_new = SO3-LayerNorm(X + delta_X)
__global__ __launch_bounds__(192) void k_xout(
    const float* __restrict__ X, const float* __restrict__ dX,
    float* __restrict__ out) {
  __shared__ float ssq[3];
  int n = blockIdx.x, tid = threadIdx.x;
  if (tid < 3) ssq[tid] = 0.f;
  __syncthreads();
  float val = 0.f; int ir = 0;
  if (tid < XROW) {
    val = X[(size_t)n * XROW + tid] + dX[(size_t)n * XROW + tid];
    int s = tid % SPH;
    ir = (s == 0) ? 0 : ((s < 4) ? 1 : 2);
    atomicAdd(&ssq[ir], val * val);
  }
  __syncthreads();
  if (tid < XROW) {
    const float cnt[3] = {16.f, 48.f, 80.f};
    float rms = sqrtf(ssq[ir] / cnt[ir] + 1e-5f);
    out[(size_t)n * XROW + tid] = val / rms;
  }
}

extern "C" void kernel_launch(void* const* d_in, const int* in_sizes, int n_in,
                              void* d_out, int out_size, void* d_ws, size_t ws_size,
                              hipStream_t stream) {
  const float* h    = (const float*)d_in[0];
  const float* X    = (const float*)d_in[1];
  const float* t_ij = (const float*)d_in[2];
  const float* sph  = (const float*)d_in[3];
  const int*   ectr = (const int*)d_in[5];
  const int*   enbr = (const int*)d_in[6];
  const float* W_rs = (const float*)d_in[7];
  const float* W1   = (const float*)d_in[8];
  const float* W2   = (const float*)d_in[9];
  const float* gam  = (const float*)d_in[10];
  const float* bet  = (const float*)d_in[11];
  const float* Wq   = (const float*)d_in[12];
  const float* Wk   = (const float*)d_in[13];
  float* out = (float*)d_out;
  float* ws  = (float*)d_ws;

  ushort*   Wt       = (ushort*)(ws + OFF_WT);
  float*    env_node = ws + OFF_ENV;
  float*    Knode    = ws + OFF_KN;
  float*    ex_buf   = ws + OFF_EX;
  float*    delta_h  = ws + OFF_DH;
  float*    delta_X  = ws + OFF_DX;
  float*    den      = ws + OFF_DEN;
  unsigned* nmax     = (unsigned*)(ws + OFF_NMAX);
  ushort*   x_buf    = (ushort*)(ws + OFF_XBUF);

  // zero delta_h, delta_X, den, nmax (contiguous; key 0 == -inf sentinel)
  hipMemsetAsync(delta_h, 0,
                 (size_t)N_NODES * (LAT + XROW + MULT + MULT) * sizeof(float), stream);
  // t_ij passthrough output
  hipMemcpyAsync(out + (size_t)N_NODES * (LAT + XROW), d_in[2],
                 (size_t)N_EDGES * LAT * sizeof(float),
                 hipMemcpyDeviceToDevice, stream);

  k_wt<<<WTCOLS, 128, 0, stream>>>(W_rs, Wt);
  k_node<<<N_NODES / 8, 256, 0, stream>>>(h, W1, W2, Wk, env_node, Knode);
  k_edge<<<N_EDGES / EM, 256, 0, stream>>>(t_ij, X, sph, ectr, enbr, Wt,
                                           env_node, delta_h, x_buf);
  k_score<<<N_EDGES / SB, 256, 0, stream>>>(t_ij, ectr, enbr, Wq, Knode,
                                            ex_buf, nmax);
  k_den<<<(N_EDGES * MULT) / 256, 256, 0, stream>>>(ectr, nmax, ex_buf, den);
  k_dx<<<((size_t)N_EDGES * XROW) / 256, 256, 0, stream>>>(ectr, ex_buf, den, x_buf, delta_X);
  k_hout<<<N_NODES, 64, 0, stream>>>(h, delta_h, gam, bet, out);
  k_xout<<<N_NODES, 192, 0, stream>>>(X, delta_X, out + (size_t)N_NODES * LAT);
}

// Round 8
// 479.193 us; speedup vs baseline: 2.0265x; 1.2408x over previous
//
#include <hip/hip_runtime.h>

#define N_NODES 8192
#define N_EDGES 65536
#define LAT 128
#define GEN 944
#define ECOLS 816   // columns of env_ij_w actually used (0..816)
#define ENVN 48
#define LINN 768
#define MULT 16
#define SPH 9
#define XROW 144  // MULT*SPH

#define EM 16      // edges per block in k_edge
#define NWT 51     // W_rs tiles (816/16)
#define WTCOLS 816 // Wt columns (W_rs only)
#define WPAD 824   // w_lds row stride (bf16 elems), padded vs 816

#define SB 64      // edges per k_score block
#define KC 16      // k-chunk rows staged per iteration

// ---- workspace layout (float offsets); total ~55 MB, well below proven size.
// env_node is now bf16 (ushort), N*816.
#define OFF_WT    ((size_t)0)                             // 816*128 ushort = 52224 fl
#define OFF_ENV   ((size_t)52224)                         // N*816 ushort = 3342336 fl
#define OFF_KN    (OFF_ENV  + (size_t)N_NODES*ECOLS/2)    // N*256  Knode (f32)
#define OFF_EX    (OFF_KN   + (size_t)N_NODES*256)        // E*16   scores->ex
#define OFF_DH    (OFF_EX   + (size_t)N_EDGES*MULT)       // N*128  delta_h   (zeroed)
#define OFF_DX    (OFF_DH   + (size_t)N_NODES*LAT)        // N*144  delta_X   (zeroed)
#define OFF_DEN   (OFF_DX   + (size_t)N_NODES*XROW)       // N*16   den       (zeroed)
#define OFF_NMAX  (OFF_DEN  + (size_t)N_NODES*MULT)       // N*16   max keys  (zeroed)
#define OFF_XBUF  (OFF_NMAX + (size_t)N_NODES*MULT)       // E*144  x (bf16 ushort)

typedef __attribute__((ext_vector_type(8))) short bf16x8;
typedef __attribute__((ext_vector_type(4))) float f32x4;

__device__ __forceinline__ unsigned fkey(float f) {
  unsigned u = __float_as_uint(f);
  return (u & 0x80000000u) ? ~u : (u | 0x80000000u);
}
__device__ __forceinline__ float fdecode(unsigned u) {
  u = (u & 0x80000000u) ? (u & 0x7fffffffu) : ~u;
  return __uint_as_float(u);
}
__device__ __forceinline__ ushort f2b(float f) {  // f32->bf16 RNE
  unsigned u = __float_as_uint(f);
  return (ushort)((u + 0x7FFFu + ((u >> 16) & 1u)) >> 16);
}
__device__ __forceinline__ float b2f(ushort u) {
  return __uint_as_float(((unsigned)u) << 16);
}

// ---------------- weight transpose+cvt: Wt[c][k] = bf16(W_rs[:,c]), c<816
__global__ __launch_bounds__(128) void k_wt(
    const float* __restrict__ W_rs, ushort* __restrict__ Wt) {
  int c = blockIdx.x;   // 0..815
  int k = threadIdx.x;  // 0..127
  Wt[(size_t)c * 128 + k] = f2b(W_rs[(size_t)k * GEN + c]);
}

// ---------------- per-node precompute: env_node(bf16) = silu(h@W1)@W2, Knode = h@W_key
__global__ __launch_bounds__(256) void k_node(
    const float* __restrict__ h, const float* __restrict__ W1,
    const float* __restrict__ W2, const float* __restrict__ Wk,
    ushort* __restrict__ env_node, float* __restrict__ Knode) {
  __shared__ float h_lds[8][LAT];
  __shared__ float s_lds[8][LAT];
  const int tid = threadIdx.x;
  const int nb = blockIdx.x * 8;

  { int o = tid * 4, e = o >> 7, k = o & 127;
    *(float4*)&h_lds[e][k] = *(const float4*)&h[(size_t)(nb + e) * LAT + k]; }
  __syncthreads();

  { // u = h@W1, silu -> s_lds
    int e = tid >> 5, c4 = (tid & 31) * 4;
    float a0 = 0, a1 = 0, a2 = 0, a3 = 0;
    for (int k0 = 0; k0 < LAT; k0 += 4) {
      float4 tv = *(float4*)&h_lds[e][k0];
      float4 w0 = *(const float4*)&W1[(k0 + 0) * LAT + c4];
      float4 w1 = *(const float4*)&W1[(k0 + 1) * LAT + c4];
      float4 w2 = *(const float4*)&W1[(k0 + 2) * LAT + c4];
      float4 w3 = *(const float4*)&W1[(k0 + 3) * LAT + c4];
      a0 += tv.x * w0.x + tv.y * w1.x + tv.z * w2.x + tv.w * w3.x;
      a1 += tv.x * w0.y + tv.y * w1.y + tv.z * w2.y + tv.w * w3.y;
      a2 += tv.x * w0.z + tv.y * w1.z + tv.z * w2.z + tv.w * w3.z;
      a3 += tv.x * w0.w + tv.y * w1.w + tv.z * w2.w + tv.w * w3.w;
    }
    s_lds[e][c4 + 0] = a0 / (1.f + expf(-a0));
    s_lds[e][c4 + 1] = a1 / (1.f + expf(-a1));
    s_lds[e][c4 + 2] = a2 / (1.f + expf(-a2));
    s_lds[e][c4 + 3] = a3 / (1.f + expf(-a3));
  }
  { // Knode = h@W_key
    int e = tid >> 5;
#pragma unroll
    for (int t2 = 0; t2 < 2; ++t2) {
      int c4 = ((tid & 31) + 32 * t2) * 4;
      float a0 = 0, a1 = 0, a2 = 0, a3 = 0;
      for (int k0 = 0; k0 < LAT; k0 += 4) {
        float4 tv = *(float4*)&h_lds[e][k0];
        float4 w0 = *(const float4*)&Wk[(k0 + 0) * 256 + c4];
        float4 w1 = *(const float4*)&Wk[(k0 + 1) * 256 + c4];
        float4 w2 = *(const float4*)&Wk[(k0 + 2) * 256 + c4];
        float4 w3 = *(const float4*)&Wk[(k0 + 3) * 256 + c4];
        a0 += tv.x * w0.x + tv.y * w1.x + tv.z * w2.x + tv.w * w3.x;
        a1 += tv.x * w0.y + tv.y * w1.y + tv.z * w2.y + tv.w * w3.y;
        a2 += tv.x * w0.z + tv.y * w1.z + tv.z * w2.z + tv.w * w3.z;
        a3 += tv.x * w0.w + tv.y * w1.w + tv.z * w2.w + tv.w * w3.w;
      }
      float4 r = make_float4(a0, a1, a2, a3);
      *(float4*)&Knode[(size_t)(nb + e) * 256 + c4] = r;
    }
  }
  __syncthreads();

  if (tid < 204) {  // env_node = bf16(s@W2) (816 cols)
    int c4 = tid * 4;
    float4 acc[8];
#pragma unroll
    for (int e = 0; e < 8; ++e) acc[e] = make_float4(0, 0, 0, 0);
    for (int k0 = 0; k0 < LAT; k0 += 4) {
      float4 w0 = *(const float4*)&W2[(size_t)(k0 + 0) * GEN + c4];
      float4 w1 = *(const float4*)&W2[(size_t)(k0 + 1) * GEN + c4];
      float4 w2 = *(const float4*)&W2[(size_t)(k0 + 2) * GEN + c4];
      float4 w3 = *(const float4*)&W2[(size_t)(k0 + 3) * GEN + c4];
#pragma unroll
      for (int e = 0; e < 8; ++e) {
        float4 tv = *(float4*)&s_lds[e][k0];
        acc[e].x += tv.x * w0.x + tv.y * w1.x + tv.z * w2.x + tv.w * w3.x;
        acc[e].y += tv.x * w0.y + tv.y * w1.y + tv.z * w2.y + tv.w * w3.y;
        acc[e].z += tv.x * w0.z + tv.y * w1.z + tv.z * w2.z + tv.w * w3.z;
        acc[e].w += tv.x * w0.w + tv.y * w1.w + tv.z * w2.w + tv.w * w3.w;
      }
    }
#pragma unroll
    for (int e = 0; e < 8; ++e) {
      ushort4 r;
      r.x = f2b(acc[e].x); r.y = f2b(acc[e].y);
      r.z = f2b(acc[e].z); r.w = f2b(acc[e].w);
      *(ushort4*)&env_node[(size_t)(nb + e) * ECOLS + c4] = r;
    }
  }
}

// ---------------- MFMA edge kernel, software-pipelined (depth-1 prefetch).
// w = ((t_hi+t_lo)@W_rs)*env_j(bf16) -> bf16 LDS (+delta_h atomics cols<128);
// then x = env_weighter + eq_linear.
__global__ __launch_bounds__(256) void k_edge(
    const float* __restrict__ t_ij, const float* __restrict__ X,
    const float* __restrict__ sph, const int* __restrict__ ectr,
    const int* __restrict__ enbr, const ushort* __restrict__ Wt,
    const ushort* __restrict__ env_node, float* __restrict__ delta_h,
    ushort* __restrict__ x_buf) {
  __shared__ ushort w_lds[EM][WPAD];        // 26368 B
  __shared__ ushort xj_lds[EM][SPH][16];    // 4608 B  (X[j] transposed, bf16)
  __shared__ float sph_lds[EM][12];         // 768 B
  __shared__ int i_lds[EM], j_lds[EM];      // 128 B
  const int tid = threadIdx.x;
  const int lane = tid & 63;
  const int wid = tid >> 6;
  const int eb = blockIdx.x * EM;
  const int r15 = lane & 15, kg = lane >> 4, kg4 = kg * 4;

  if (tid < EM) { i_lds[tid] = ectr[eb + tid]; j_lds[tid] = enbr[eb + tid]; }
  if (tid < EM * SPH) {
    int e = tid / 9, s = tid % 9;
    sph_lds[e][s] = sph[(size_t)(eb + e) * SPH + s];
  }
  for (int o = tid; o < EM * XROW; o += 256) {  // transpose-stage X[j], bf16
    int e = o / XROW, rr = o % XROW, v = rr / 9, s = rr % 9;
    xj_lds[e][s][v] = f2b(X[(size_t)enbr[eb + e] * XROW + rr]);
  }

  // A fragments (hi + residual lo); all 4 waves hold the same 16 t rows
  bf16x8 ahi[4], alo[4];
#pragma unroll
  for (int c = 0; c < 4; ++c) {
    const float* src = &t_ij[(size_t)(eb + r15) * LAT + c * 32 + kg * 8];
    float f[8];
    *(float4*)&f[0] = *(const float4*)src;
    *(float4*)&f[4] = *(const float4*)(src + 4);
    bf16x8 hh, ll;
#pragma unroll
    for (int d = 0; d < 8; ++d) {
      ushort hb = f2b(f[d]);
      hh[d] = hb;
      ll[d] = f2b(f[d] - b2f(hb));
    }
    ahi[c] = hh; alo[c] = ll;
  }
  __syncthreads();

  // hoist per-lane gather bases
  int jrow[4], irow[4];
#pragma unroll
  for (int g = 0; g < 4; ++g) {
    jrow[g] = j_lds[kg4 + g] * ECOLS;
    irow[g] = i_lds[kg4 + g] * LAT;
  }

  // pipelined tile loop: prefetch tile tn+4 while computing tn
  bf16x8 bA[4]; ushort eA[4];
  {
    const ushort* b0 = &Wt[(size_t)(wid * 16 + r15) * 128 + kg * 8];
#pragma unroll
    for (int c = 0; c < 4; ++c) bA[c] = *(const bf16x8*)(b0 + c * 32);
    int col = wid * 16 + r15;
#pragma unroll
    for (int g = 0; g < 4; ++g) eA[g] = env_node[(size_t)jrow[g] + col];
  }
  for (int tn = wid; tn < NWT; tn += 4) {
    const int tn2 = tn + 4;
    bf16x8 bB[4]; ushort eB[4];
    if (tn2 < NWT) {
      const ushort* b0 = &Wt[(size_t)(tn2 * 16 + r15) * 128 + kg * 8];
#pragma unroll
      for (int c = 0; c < 4; ++c) bB[c] = *(const bf16x8*)(b0 + c * 32);
      int col2 = tn2 * 16 + r15;
#pragma unroll
      for (int g = 0; g < 4; ++g) eB[g] = env_node[(size_t)jrow[g] + col2];
    }
    f32x4 acc = {0.f, 0.f, 0.f, 0.f};
#pragma unroll
    for (int c = 0; c < 4; ++c) {
      acc = __builtin_amdgcn_mfma_f32_16x16x32_bf16(ahi[c], bA[c], acc, 0, 0, 0);
      acc = __builtin_amdgcn_mfma_f32_16x16x32_bf16(alo[c], bA[c], acc, 0, 0, 0);
    }
    int col = tn * 16 + r15;
#pragma unroll
    for (int g = 0; g < 4; ++g) {
      float v = acc[g] * b2f(eA[g]);
      w_lds[kg4 + g][col] = f2b(v);
      if (tn < 8)
        atomicAdd(&delta_h[(size_t)irow[g] + col], v);
    }
    if (tn2 < NWT) {
#pragma unroll
      for (int c = 0; c < 4; ++c) bA[c] = bB[c];
#pragma unroll
      for (int g = 0; g < 4; ++g) eA[g] = eB[g];
    }
  }
  __syncthreads();

  // x = delta_spharm + delta_eq: thread = (edge e, mult m); store bf16
  {
    int e = tid >> 4, m = tid & 15;
    float lw[3][16], ew[3];
#pragma unroll
    for (int ir = 0; ir < 3; ++ir) {
      const ushort* p = &w_lds[e][ENVN + ir * 256 + m * 16];
      uint4 q0 = *(const uint4*)p;
      uint4 q1 = *(const uint4*)(p + 8);
      unsigned qq[8] = {q0.x, q0.y, q0.z, q0.w, q1.x, q1.y, q1.z, q1.w};
#pragma unroll
      for (int d = 0; d < 8; ++d) {
        lw[ir][2 * d]     = __uint_as_float(qq[d] << 16);
        lw[ir][2 * d + 1] = __uint_as_float(qq[d] & 0xFFFF0000u);
      }
      ew[ir] = b2f(w_lds[e][ir * 16 + m]);
    }
    ushort* xp = &x_buf[((size_t)(eb + e) * MULT + m) * SPH];
#pragma unroll
    for (int s = 0; s < SPH; ++s) {
      int ir = (s == 0) ? 0 : ((s < 4) ? 1 : 2);
      const ushort* xr = xj_lds[e][s];
      uint4 x0 = *(const uint4*)xr;
      uint4 x1 = *(const uint4*)(xr + 8);
      unsigned xx[8] = {x0.x, x0.y, x0.z, x0.w, x1.x, x1.y, x1.z, x1.w};
      float acc = sph_lds[e][s] * ew[ir];
#pragma unroll
      for (int d = 0; d < 8; ++d) {
        float v0 = __uint_as_float(xx[d] << 16);
        float v1 = __uint_as_float(xx[d] & 0xFFFF0000u);
        acc += 0.25f * (lw[ir][2 * d] * v0 + lw[ir][2 * d + 1] * v1);
      }
      xp[s] = f2b(acc);
    }
  }
}

// ---------------- f32 scores, LDS-tiled GEMM structure (validated r7).
__global__ __launch_bounds__(256) void k_score(
    const float* __restrict__ t_ij, const int* __restrict__ ectr,
    const int* __restrict__ enbr, const float* __restrict__ Wq,
    const float* __restrict__ Knode, float* __restrict__ ex_buf,
    unsigned* __restrict__ nmax) {
  __shared__ float t_lds[SB][129];
  __shared__ float wq_lds[KC][260];
  const int tid = threadIdx.x;
  const int eb = blockIdx.x * SB;
  const int m = tid & 15, eg = tid >> 4;
  const int rot = (m >> 1) & 3;

#pragma unroll
  for (int p = 0; p < 8; ++p) {
    int qi = tid + p * 256;
    int e = qi >> 5, kq = (qi & 31) * 4;
    float4 v = *(const float4*)&t_ij[(size_t)(eb + e) * LAT + kq];
    t_lds[e][kq + 0] = v.x; t_lds[e][kq + 1] = v.y;
    t_lds[e][kq + 2] = v.z; t_lds[e][kq + 3] = v.w;
  }

  float qa[4][16];
#pragma unroll
  for (int e = 0; e < 4; ++e)
#pragma unroll
    for (int hh = 0; hh < 16; ++hh) qa[e][hh] = 0.f;

  for (int kc = 0; kc < LAT; kc += KC) {
    __syncthreads();
#pragma unroll
    for (int p = 0; p < 4; ++p) {
      int idx = tid + p * 256;
      int kr = idx >> 6, c4 = (idx & 63) * 4;
      int mm = c4 >> 4, h4 = (c4 >> 2) & 3;
      int c4s = mm * 16 + ((h4 + (mm >> 1)) & 3) * 4;
      float4 v = *(const float4*)&Wq[(size_t)(kc + kr) * 256 + c4];
      *(float4*)&wq_lds[kr][c4s] = v;
    }
    __syncthreads();
#pragma unroll 2
    for (int kk = 0; kk < KC; ++kk) {
      float w[16];
#pragma unroll
      for (int i = 0; i < 4; ++i) {
        float4 wv = *(const float4*)&wq_lds[kk][m * 16 + ((i + rot) & 3) * 4];
        w[i * 4 + 0] = wv.x; w[i * 4 + 1] = wv.y;
        w[i * 4 + 2] = wv.z; w[i * 4 + 3] = wv.w;
      }
#pragma unroll
      for (int e = 0; e < 4; ++e) {
        float tv = t_lds[eg * 4 + e][kc + kk];
#pragma unroll
        for (int hh = 0; hh < 16; ++hh) qa[e][hh] += tv * w[hh];
      }
    }
  }

#pragma unroll
  for (int e = 0; e < 4; ++e) {
    int ee = eb + eg * 4 + e;
    int j = enbr[ee];
    const float* kn = &Knode[(size_t)j * 256 + m * 16];
    float4 k0 = *(const float4*)kn;
    float4 k1 = *(const float4*)(kn + 4);
    float4 k2 = *(const float4*)(kn + 8);
    float4 k3 = *(const float4*)(kn + 12);
    float acc =
        qa[e][0] * k0.x + qa[e][1] * k0.y + qa[e][2] * k0.z + qa[e][3] * k0.w +
        qa[e][4] * k1.x + qa[e][5] * k1.y + qa[e][6] * k1.z + qa[e][7] * k1.w +
        qa[e][8] * k2.x + qa[e][9] * k2.y + qa[e][10] * k2.z + qa[e][11] * k2.w +
        qa[e][12] * k3.x + qa[e][13] * k3.y + qa[e][14] * k3.z + qa[e][15] * k3.w;
    float sc = 4.f * acc;
    ex_buf[(size_t)ee * MULT + m] = sc;
    atomicMax(&nmax[ectr[ee] * MULT + m], fkey(sc));
  }
}

// ---------------- softmax pass 2: ex = exp(s - max), den scatter
__global__ __launch_bounds__(256) void k_den(
    const int* __restrict__ ectr, const unsigned* __restrict__ nmax,
    float* __restrict__ ex_buf, float* __restrict__ den) {
  int idx = blockIdx.x * 256 + threadIdx.x;
  int e = idx >> 4, m = idx & 15;
  int i = ectr[e];
  float mval = fdecode(nmax[i * MULT + m]);
  float ex = expf(ex_buf[idx] - mval);
  ex_buf[idx] = ex;
  atomicAdd(&den[i * MULT + m], ex);
}

// ---------------- delta_X scatter: delta_X[i] += x * alpha
__global__ __launch_bounds__(256) void k_dx(
    const int* __restrict__ ectr, const float* __restrict__ ex_buf,
    const float* __restrict__ den, const ushort* __restrict__ x_buf,
    float* __restrict__ delta_X) {
  size_t idx = (size_t)blockIdx.x * 256 + threadIdx.x;
  int e = (int)(idx / XROW), r = (int)(idx % XROW), m = r / SPH;
  int i = ectr[e];
  float alpha = ex_buf[(size_t)e * MULT + m] / (den[i * MULT + m] + 1e-20f);
  atomicAdd(&delta_X[(size_t)i * XROW + r], b2f(x_buf[idx]) * alpha);
}

// ---------------- h_new = LayerNorm(h + delta_h)
__global__ __launch_bounds__(64) void k_hout(
    const float* __restrict__ h, const float* __restrict__ dh,
    const float* __restrict__ gamma, const float* __restrict__ beta,
    float* __restrict__ out) {
  int n = blockIdx.x, lane = threadIdx.x;
  size_t base = (size_t)n * LAT + lane * 2;
  float2 hv = *(const float2*)&h[base];
  float2 dv = *(const float2*)&dh[base];
  float v0 = hv.x + dv.x, v1 = hv.y + dv.y;
  float s = v0 + v1, ss = v0 * v0 + v1 * v1;
#pragma unroll
  for (int o = 32; o; o >>= 1) { s += __shfl_xor(s, o); ss += __shfl_xor(ss, o); }
  float mean = s * (1.f / 128.f);
  float var = ss * (1.f / 128.f) - mean * mean;
  float inv = rsqrtf(var + 1e-5f);
  int c = lane * 2;
  out[base + 0] = (v0 - mean) * inv * gamma[c + 0] + beta[c + 0];
  out[base + 1] = (v1 - mean) * inv * gamma[c + 1] + beta[c + 1];
}

// ---------------- X_new = SO3-LayerNorm(X + delta_X)
__global__ __launch_bounds__(192) void k_xout(
    const float* __restrict__ X, const float* __restrict__ dX,
    float* __restrict__ out) {
  __shared__ float ssq[3];
  int n = blockIdx.x, tid = threadIdx.x;
  if (tid < 3) ssq[tid] = 0.f;
  __syncthreads();
  float val = 0.f; int ir = 0;
  if (tid < XROW) {
    val = X[(size_t)n * XROW + tid] + dX[(size_t)n * XROW + tid];
    int s = tid % SPH;
    ir = (s == 0) ? 0 : ((s < 4) ? 1 : 2);
    atomicAdd(&ssq[ir], val * val);
  }
  __syncthreads();
  if (tid < XROW) {
    const float cnt[3] = {16.f, 48.f, 80.f};
    float rms = sqrtf(ssq[ir] / cnt[ir] + 1e-5f);
    out[(size_t)n * XROW + tid] = val / rms;
  }
}

extern "C" void kernel_launch(void* const* d_in, const int* in_sizes, int n_in,
                              void* d_out, int out_size, void* d_ws, size_t ws_size,
                              hipStream_t stream) {
  const float* h    = (const float*)d_in[0];
  const float* X    = (const float*)d_in[1];
  const float* t_ij = (const float*)d_in[2];
  const float* sph  = (const float*)d_in[3];
  const int*   ectr = (const int*)d_in[5];
  const int*   enbr = (const int*)d_in[6];
  const float* W_rs = (const float*)d_in[7];
  const float* W1   = (const float*)d_in[8];
  const float* W2   = (const float*)d_in[9];
  const float* gam  = (const float*)d_in[10];
  const float* bet  = (const float*)d_in[11];
  const float* Wq   = (const float*)d_in[12];
  const float* Wk   = (const float*)d_in[13];
  float* out = (float*)d_out;
  float* ws  = (float*)d_ws;

  ushort*   Wt       = (ushort*)(ws + OFF_WT);
  ushort*   env_node = (ushort*)(ws + OFF_ENV);
  float*    Knode    = ws + OFF_KN;
  float*    ex_buf   = ws + OFF_EX;
  float*    delta_h  = ws + OFF_DH;
  float*    delta_X  = ws + OFF_DX;
  float*    den      = ws + OFF_DEN;
  unsigned* nmax     = (unsigned*)(ws + OFF_NMAX);
  ushort*   x_buf    = (ushort*)(ws + OFF_XBUF);

  // zero delta_h, delta_X, den, nmax (contiguous; key 0 == -inf sentinel)
  hipMemsetAsync(delta_h, 0,
                 (size_t)N_NODES * (LAT + XROW + MULT + MULT) * sizeof(float), stream);
  // t_ij passthrough output
  hipMemcpyAsync(out + (size_t)N_NODES * (LAT + XROW), d_in[2],
                 (size_t)N_EDGES * LAT * sizeof(float),
                 hipMemcpyDeviceToDevice, stream);

  k_wt<<<WTCOLS, 128, 0, stream>>>(W_rs, Wt);
  k_node<<<N_NODES / 8, 256, 0, stream>>>(h, W1, W2, Wk, env_node, Knode);
  k_edge<<<N_EDGES / EM, 256, 0, stream>>>(t_ij, X, sph, ectr, enbr, Wt,
                                           env_node, delta_h, x_buf);
  k_score<<<N_EDGES / SB, 256, 0, stream>>>(t_ij, ectr, enbr, Wq, Knode,
                                            ex_buf, nmax);
  k_den<<<(N_EDGES * MULT) / 256, 256, 0, stream>>>(ectr, nmax, ex_buf, den);
  k_dx<<<((size_t)N_EDGES * XROW) / 256, 256, 0, stream>>>(ectr, ex_buf, den, x_buf, delta_X);
  k_hout<<<N_NODES, 64, 0, stream>>>(h, delta_h, gam, bet, out);
  k_xout<<<N_NODES, 192, 0, stream>>>(X, delta_X, out + (size_t)N_NODES * LAT);
}